// Round 6
// baseline (319.583 us; speedup 1.0000x reference)
//
#include <hip/hip_runtime.h>
#include <math.h>

// Problem constants: B=32, H=1024, W=1024, N=100000
#define RD_H 1024
#define RD_W 1024
#define RD_N 100000
#define RD_B 32
#define BDIM 256
#define NXCD 8
#define IMGS_PER_XCD 4                 // 32 images / 8 XCDs
#define IMG_PIX (RD_H * RD_W)          // 4 MB per image

// A-sorted binning geometry: key = bandA*1024 + rank  (17 bits exactly)
#define NBANDS 128
#define BAND_ROWS 8                    // 128 bands x 8 rows; 32 KB LDS band
#define ACAP 1024                      // A cap (key structure); mean 781 + 8.7s
#define BCAP 1280                      // B cap; mean 781 + 17.9s
#define KEYS_PER_IMG (NBANDS * ACAP)   // 131072
#define P0_UNROLL 8
#define P0_PTS (BDIM * P0_UNROLL)      // 2048 points per bin block
#define P0_CHUNKS 49                   // ceil(100000/2048); tail = 1696 (div 8)
#define DEADBIT 0x80000000u

// Workspace layout (bytes, all 16-aligned)
#define OFF_CTRA 0u                              // 32*128*4      = 16384
#define OFF_CTRB 16384u                          //               = 16384
#define OFF_AREC 32768u                          // 32*128*1024*2 = 8388608
#define OFF_BREC 8421376u                        // 32*128*1280*4 = 20971520
#define OFF_ZA   29392896u                       // 32*131072*4   = 16777216
#define OFF_ZB   46170112u                       // 32*131072*4   = 16777216
#define OFF_ORDP 62947328u                       // 32*131072     = 4194304
#define WS_NEED  67141632u                       // ~64 MiB

typedef __attribute__((address_space(3))) void lds_void;
typedef const __attribute__((address_space(1))) void gbl_void;
typedef __attribute__((ext_vector_type(4))) int   ivec4;
typedef __attribute__((ext_vector_type(4))) float fvec4;

__device__ __forceinline__ float rd_term(float za, float zb, int od) {
    float diff = za - zb;
    float gt   = (float)(od - 1);        // {-1, 0, 1}
    float mask = fabsf(gt);              // {0, 1}
    // stable softplus(-gt*diff) = max(x,0) + log1p(exp(-|x|))
    float x  = -gt * diff;
    float sp = fmaxf(x, 0.0f) + log1pf(__expf(-fabsf(x)));
    return mask * sp + (1.0f - mask) * diff * diff;
}

// ---------------------------------------------------------------------------
// Pass I: init out + both counter arrays (8192 u32).
__global__ void rd_init_kernel(float* out, unsigned* ctrs) {
    int i = blockIdx.x * blockDim.x + threadIdx.x;
    if (i == 0) out[0] = 0.0f;
    if (i < 2 * RD_B * NBANDS) ctrs[i] = 0;
}

// ---------------------------------------------------------------------------
// Pass II: A-sorted bin. Each point gets key = bandA*1024 + global A-rank.
// A-record u16 = x(10)<<5 | yoff(3)<<2 | ord(2)   (position in region = key!)
// B-record u32 = DEAD(1)<<31 | x(10)<<20 | yoff(3)<<17 | key(17)
// Both counting-sorted in LDS, drained band-contiguous (coalesced stores).
__global__ __launch_bounds__(BDIM) void rd_bin_kernel(
    const int* __restrict__ xA, const int* __restrict__ yA,
    const int* __restrict__ xB, const int* __restrict__ yB,
    const int* __restrict__ ordin,
    unsigned* __restrict__ ctrA, unsigned* __restrict__ ctrB,
    unsigned short* __restrict__ arec, unsigned* __restrict__ brec)
{
    __shared__ unsigned histA[NBANDS], histB[NBANDS];       // counts -> cursors
    __shared__ unsigned scanA[NBANDS + 1], scanB[NBANDS + 1]; // exclusive prefix
    __shared__ unsigned gbaseA[NBANDS], gbaseB[NBANDS];     // global bases
    __shared__ unsigned short srtA[P0_PTS];                 // 4 KB
    __shared__ unsigned       srtB[P0_PTS];                 // 8 KB
    __shared__ unsigned char  sbA[P0_PTS], sbB[P0_PTS];     // 2+2 KB

    // img -> XCD pinning (matches gather/loss): records stay in that XCD's L2.
    const int xcd   = blockIdx.x & (NXCD - 1);
    const int k     = blockIdx.x / NXCD;            // 0..195
    const int img   = xcd * IMGS_PER_XCD + k / P0_CHUNKS;
    const int chunk = k % P0_CHUNKS;
    const int tid   = threadIdx.x;

    if (tid < NBANDS) { histA[tid] = 0; histB[tid] = 0; }
    __syncthreads();

    const int  n0    = chunk * P0_PTS + tid * P0_UNROLL;
    const bool activ = (n0 < RD_N);     // tail chunk 1696 = 212*8: all-8-or-none
    const long i0    = (long)img * RD_N + n0;

    int xa[8], ya[8], xb[8], yb[8], od[8];
    if (activ) {
        #pragma unroll
        for (int v = 0; v < 2; ++v) {
            ivec4 a = __builtin_nontemporal_load((const ivec4*)(xA + i0) + v);
            ivec4 b = __builtin_nontemporal_load((const ivec4*)(yA + i0) + v);
            ivec4 c = __builtin_nontemporal_load((const ivec4*)(xB + i0) + v);
            ivec4 d = __builtin_nontemporal_load((const ivec4*)(yB + i0) + v);
            ivec4 e = __builtin_nontemporal_load((const ivec4*)(ordin + i0) + v);
            #pragma unroll
            for (int q = 0; q < 4; ++q) {
                xa[4*v+q] = a[q]; ya[4*v+q] = b[q];
                xb[4*v+q] = c[q]; yb[4*v+q] = d[q]; od[4*v+q] = e[q];
            }
        }
        #pragma unroll
        for (int j = 0; j < P0_UNROLL; ++j) {
            atomicAdd(&histA[ya[j] >> 3], 1u);
            atomicAdd(&histB[yb[j] >> 3], 1u);
        }
    }
    __syncthreads();

    // snapshot counts, then parallel inclusive scan (Hillis-Steele, in place)
    unsigned cA = 0, cB = 0;
    if (tid < NBANDS) { cA = histA[tid]; cB = histB[tid]; }
    for (int off = 1; off < NBANDS; off <<= 1) {
        unsigned aA = 0, aB = 0;
        if (tid < NBANDS && tid >= off) { aA = histA[tid-off]; aB = histB[tid-off]; }
        __syncthreads();
        if (tid < NBANDS) { histA[tid] += aA; histB[tid] += aB; }
        __syncthreads();
    }
    if (tid < NBANDS) {
        scanA[tid] = histA[tid] - cA;            // exclusive prefix
        scanB[tid] = histB[tid] - cB;
        if (tid == NBANDS - 1) { scanA[NBANDS] = histA[tid]; scanB[NBANDS] = histB[tid]; }
        gbaseA[tid] = cA ? atomicAdd(&ctrA[img * NBANDS + tid], cA) : 0u;
        gbaseB[tid] = cB ? atomicAdd(&ctrB[img * NBANDS + tid], cB) : 0u;
    }
    __syncthreads();
    if (tid < NBANDS) { histA[tid] = 0; histB[tid] = 0; }   // reuse as cursors
    __syncthreads();

    // rank-assign + LDS counting-sort scatter (bank-level cost, no lines)
    if (activ) {
        #pragma unroll
        for (int j = 0; j < P0_UNROLL; ++j) {
            const int bA = ya[j] >> 3;
            const unsigned rA   = atomicAdd(&histA[bA], 1u);
            const unsigned slot = scanA[bA] + rA;
            srtA[slot] = (unsigned short)(((unsigned)xa[j] << 5) |
                                          ((unsigned)(ya[j] & 7) << 2) |
                                          (unsigned)od[j]);
            sbA[slot]  = (unsigned char)bA;
            const unsigned aidx = gbaseA[bA] + rA;
            const unsigned key  = (aidx < ACAP) ? ((unsigned)bA * ACAP + aidx)
                                                : DEADBIT;
            const int bB = yb[j] >> 3;
            const unsigned rB    = atomicAdd(&histB[bB], 1u);
            const unsigned slot2 = scanB[bB] + rB;
            srtB[slot2] = (key & DEADBIT) ? DEADBIT
                          : (((unsigned)xb[j] << 20) |
                             ((unsigned)(yb[j] & 7) << 17) | key);
            sbB[slot2]  = (unsigned char)bB;
        }
    }
    __syncthreads();

    // coalesced drains (consecutive slots -> consecutive global addresses)
    const unsigned totA = scanA[NBANDS], totB = scanB[NBANDS];
    unsigned short* __restrict__ arimg = arec + (size_t)img * NBANDS * ACAP;
    for (unsigned s = tid; s < totA; s += BDIM) {
        const unsigned b   = sbA[s];
        const unsigned idx = gbaseA[b] + (s - scanA[b]);
        if (idx < ACAP) arimg[(size_t)b * ACAP + idx] = srtA[s];
    }
    unsigned* __restrict__ brimg = brec + (size_t)img * NBANDS * BCAP;
    for (unsigned s = tid; s < totB; s += BDIM) {
        const unsigned b   = sbB[s];
        const unsigned idx = gbaseB[b] + (s - scanB[b]);
        if (idx < BCAP) brimg[(size_t)b * BCAP + idx] = srtB[s];
    }
}

// ---------------------------------------------------------------------------
// Pass III: per (img, band): stage 32 KB depth band in LDS.
// A-side: coalesced zA/ord writes at sequential keys (nontemporal: stream-out).
// B-side: the one surviving scatter, into L2-resident zB (2 MB per XCD).
__global__ __launch_bounds__(BDIM) void rd_gather_kernel(
    const float* __restrict__ depth,
    const unsigned* __restrict__ ctrA, const unsigned* __restrict__ ctrB,
    const unsigned short* __restrict__ arec, const unsigned* __restrict__ brec,
    float* __restrict__ zA, float* __restrict__ zB,
    unsigned char* __restrict__ ordp)
{
    __shared__ float band_lds[BAND_ROWS * RD_W];   // 32 KB -> 4-5 blocks/CU

    const int xcd  = blockIdx.x & (NXCD - 1);
    const int k    = blockIdx.x / NXCD;            // 0..511
    const int img  = xcd * IMGS_PER_XCD + (k >> 7);
    const int band = k & (NBANDS - 1);
    const int tid  = threadIdx.x;

    const float* src = depth + (size_t)img * IMG_PIX + (size_t)band * BAND_ROWS * RD_W;
    #pragma unroll
    for (int c = 0; c < 8; ++c) {
        const int f4 = c * BDIM + tid;
        __builtin_amdgcn_global_load_lds(
            (gbl_void*)((const fvec4*)src + f4),
            (lds_void*)&band_lds[(c * BDIM + (tid & ~63)) * 4],
            16, 0, 0);
    }
    __syncthreads();   // drains vmcnt before barrier

    const unsigned cA = min(ctrA[img * NBANDS + band], (unsigned)ACAP);
    const unsigned cB = min(ctrB[img * NBANDS + band], (unsigned)BCAP);
    const unsigned short* __restrict__ ar = arec + (size_t)(img * NBANDS + band) * ACAP;
    const unsigned*       __restrict__ br = brec + (size_t)(img * NBANDS + band) * BCAP;
    float*         __restrict__ zAp  = zA   + (size_t)img * KEYS_PER_IMG + band * ACAP;
    unsigned char* __restrict__ op   = ordp + (size_t)img * KEYS_PER_IMG + band * ACAP;
    float*         __restrict__ zBim = zB   + (size_t)img * KEYS_PER_IMG;

    for (unsigned i = tid; i < cA; i += BDIM) {     // coalesced in AND out
        const unsigned r = ar[i];
        const float z = band_lds[((r >> 2) & 7) * RD_W + (r >> 5)];
        __builtin_nontemporal_store(z, zAp + i);
        __builtin_nontemporal_store((unsigned char)(r & 3), op + i);
    }
    for (unsigned i = tid; i < cB; i += BDIM) {     // coalesced in, scatter out
        const unsigned r = br[i];
        if (r & DEADBIT) continue;
        const float z = band_lds[((r >> 17) & 7) * RD_W + ((r >> 20) & 1023)];
        zBim[r & 0x1FFFF] = z;                      // L2-resident target
    }
}

// ---------------------------------------------------------------------------
// Pass IV: streaming combine in key order; validity from ctrA.
__global__ __launch_bounds__(BDIM) void rd_loss_kernel(
    const float* __restrict__ zA, const float* __restrict__ zB,
    const unsigned char* __restrict__ ordp, const unsigned* __restrict__ ctrA,
    float* __restrict__ out, float inv_total)
{
    const int xcd  = blockIdx.x & (NXCD - 1);
    const int k    = blockIdx.x / NXCD;
    const int img  = xcd * IMGS_PER_XCD + (k >> 7);
    const int band = k & (NBANDS - 1);
    const int tid  = threadIdx.x;

    const unsigned cA   = min(ctrA[img * NBANDS + band], (unsigned)ACAP);
    const size_t   base = (size_t)img * KEYS_PER_IMG + band * ACAP;

    float loss = 0.0f;
    const unsigned i0 = (unsigned)tid * 4;          // 1024 = 256*4 keys/block
    if (i0 < cA) {
        const fvec4 a = __builtin_nontemporal_load((const fvec4*)(zA + base) + tid);
        const fvec4 b = *((const fvec4*)(zB + base) + tid);   // L2-hot (same XCD)
        const unsigned o4 = __builtin_nontemporal_load((const unsigned*)(ordp + base) + tid);
        #pragma unroll
        for (int e = 0; e < 4; ++e)
            if (i0 + e < cA)
                loss += rd_term(a[e], b[e], (int)((o4 >> (8 * e)) & 3u));
    }

    #pragma unroll
    for (int off = 32; off > 0; off >>= 1)
        loss += __shfl_down(loss, off, 64);

    __shared__ float wsum[BDIM / 64];
    const int lane = tid & 63, wid = tid >> 6;
    if (lane == 0) wsum[wid] = loss;
    __syncthreads();
    if (tid == 0) {
        float s = 0.0f;
        #pragma unroll
        for (int w = 0; w < BDIM / 64; ++w) s += wsum[w];
        atomicAdd(out, s * inv_total);
    }
}

// ---------------------------------------------------------------------------
// Fallback (proven round-0 kernel) if workspace too small / shape changes.
#define FB_UNROLL 8
#define FB_KPB 196
__global__ void rd_zero_kernel(float* out) { out[0] = 0.0f; }
__global__ __launch_bounds__(BDIM) void rd_loss_fallback(
    const float* __restrict__ depth,
    const int* __restrict__ xA, const int* __restrict__ yA,
    const int* __restrict__ xB, const int* __restrict__ yB,
    const int* __restrict__ ord,
    float* __restrict__ out, int total, float inv_total)
{
    int v  = (blockIdx.x % NXCD) * FB_KPB + (blockIdx.x / NXCD);
    int i0 = (v * BDIM + threadIdx.x) * FB_UNROLL;
    float loss = 0.0f;
    if (i0 < total) {
        int b = i0 / RD_N;
        const float* img = depth + (long)b * IMG_PIX;
        int4 xa[2] = {((const int4*)(xA+i0))[0], ((const int4*)(xA+i0))[1]};
        int4 ya[2] = {((const int4*)(yA+i0))[0], ((const int4*)(yA+i0))[1]};
        int4 xb[2] = {((const int4*)(xB+i0))[0], ((const int4*)(xB+i0))[1]};
        int4 yb[2] = {((const int4*)(yB+i0))[0], ((const int4*)(yB+i0))[1]};
        int4 od[2] = {((const int4*)(ord+i0))[0], ((const int4*)(ord+i0))[1]};
        const int* xap = (const int*)xa; const int* yap = (const int*)ya;
        const int* xbp = (const int*)xb; const int* ybp = (const int*)yb;
        const int* odp = (const int*)od;
        float za[FB_UNROLL], zb[FB_UNROLL];
        #pragma unroll
        for (int j = 0; j < FB_UNROLL; ++j) za[j] = img[yap[j]*RD_W + xap[j]];
        #pragma unroll
        for (int j = 0; j < FB_UNROLL; ++j) zb[j] = img[ybp[j]*RD_W + xbp[j]];
        #pragma unroll
        for (int j = 0; j < FB_UNROLL; ++j) loss += rd_term(za[j], zb[j], odp[j]);
    }
    #pragma unroll
    for (int off = 32; off > 0; off >>= 1) loss += __shfl_down(loss, off, 64);
    __shared__ float wsum[BDIM / 64];
    int lane = threadIdx.x & 63, wid = threadIdx.x >> 6;
    if (lane == 0) wsum[wid] = loss;
    __syncthreads();
    if (threadIdx.x == 0) {
        float s = 0.0f;
        #pragma unroll
        for (int w = 0; w < BDIM / 64; ++w) s += wsum[w];
        atomicAdd(out, s * inv_total);
    }
}

// ---------------------------------------------------------------------------
extern "C" void kernel_launch(void* const* d_in, const int* in_sizes, int n_in,
                              void* d_out, int out_size, void* d_ws, size_t ws_size,
                              hipStream_t stream) {
    const float* depth = (const float*)d_in[0];
    const int*   xA    = (const int*)d_in[1];
    const int*   yA    = (const int*)d_in[2];
    const int*   xB    = (const int*)d_in[3];
    const int*   yB    = (const int*)d_in[4];
    const int*   ord   = (const int*)d_in[5];
    float* out = (float*)d_out;

    const int total = in_sizes[1];               // B*N = 3,200,000
    const float inv_total = 1.0f / (float)total;

    if (ws_size < WS_NEED || total != RD_B * RD_N) {
        rd_zero_kernel<<<1, 1, 0, stream>>>(out);
        rd_loss_fallback<<<NXCD * FB_KPB, BDIM, 0, stream>>>(
            depth, xA, yA, xB, yB, ord, out, total, inv_total);
        return;
    }

    unsigned*       ctrA = (unsigned*)((char*)d_ws + OFF_CTRA);
    unsigned*       ctrB = (unsigned*)((char*)d_ws + OFF_CTRB);
    unsigned short* arec = (unsigned short*)((char*)d_ws + OFF_AREC);
    unsigned*       brec = (unsigned*)((char*)d_ws + OFF_BREC);
    float*          zA   = (float*)((char*)d_ws + OFF_ZA);
    float*          zB   = (float*)((char*)d_ws + OFF_ZB);
    unsigned char*  ordp = (unsigned char*)((char*)d_ws + OFF_ORDP);

    rd_init_kernel<<<32, BDIM, 0, stream>>>(out, ctrA);            // zeroes A+B ctrs
    rd_bin_kernel<<<NXCD * IMGS_PER_XCD * P0_CHUNKS, BDIM, 0, stream>>>(   // 1568
        xA, yA, xB, yB, ord, ctrA, ctrB, arec, brec);
    rd_gather_kernel<<<NXCD * IMGS_PER_XCD * NBANDS, BDIM, 0, stream>>>(   // 4096
        depth, ctrA, ctrB, arec, brec, zA, zB, ordp);
    rd_loss_kernel<<<NXCD * IMGS_PER_XCD * NBANDS, BDIM, 0, stream>>>(     // 4096
        zA, zB, ordp, ctrA, out, inv_total);
}

// Round 7
// 263.773 us; speedup vs baseline: 1.2116x; 1.2116x over previous
//
#include <hip/hip_runtime.h>
#include <math.h>

// Problem constants (from reference): B=32, H=1024, W=1024, N=100000
#define RD_H 1024
#define RD_W 1024
#define RD_N 100000
#define BDIM 256
#define UNROLL 8        // N % 8 == 0 -> all 8 points of a thread share one batch index
#define NXCD 8
#define KPB  196        // blocks per XCD slice; 8*196=1568 blocks >= 1563 needed

__global__ void rd_zero_kernel(float* out) { out[0] = 0.0f; }

__global__ __launch_bounds__(BDIM) void rd_loss_kernel(
    const float* __restrict__ depth,   // (B, H, W) fp32
    const int*   __restrict__ xA,
    const int*   __restrict__ yA,
    const int*   __restrict__ xB,
    const int*   __restrict__ yB,
    const int*   __restrict__ ord,
    float* __restrict__ out,
    int total, float inv_total)
{
    // XCD-locality swizzle: blocks dispatch round-robin over 8 XCDs
    // (blockIdx%8 -> XCD). Remap so XCD x processes consecutive point ranges
    // in time order -> active image (4 MB) stays resident in that XCD's 4 MB L2.
    int v  = (blockIdx.x % NXCD) * KPB + (blockIdx.x / NXCD);
    int i0 = (v * BDIM + threadIdx.x) * UNROLL;

    float loss = 0.0f;
    if (i0 < total) {
        // All UNROLL consecutive points share one batch (RD_N % UNROLL == 0).
        int b = i0 / RD_N;
        const float* img = depth + (long)b * (RD_H * RD_W);

        // Vectorized, fully-coalesced index loads: 2x int4 per array.
        const int4* xA4 = (const int4*)(xA + i0);
        const int4* yA4 = (const int4*)(yA + i0);
        const int4* xB4 = (const int4*)(xB + i0);
        const int4* yB4 = (const int4*)(yB + i0);
        const int4* or4 = (const int4*)(ord + i0);
        int4 xa[2] = {xA4[0], xA4[1]};
        int4 ya[2] = {yA4[0], yA4[1]};
        int4 xb[2] = {xB4[0], xB4[1]};
        int4 yb[2] = {yB4[0], yB4[1]};
        int4 od[2] = {or4[0], or4[1]};

        const int* xap = (const int*)xa;
        const int* yap = (const int*)ya;
        const int* xbp = (const int*)xb;
        const int* ybp = (const int*)yb;
        const int* odp = (const int*)od;

        // Issue all 16 gathers before any use -> 16 loads in flight per thread.
        float za[UNROLL], zb[UNROLL];
        #pragma unroll
        for (int j = 0; j < UNROLL; ++j)
            za[j] = img[yap[j] * RD_W + xap[j]];
        #pragma unroll
        for (int j = 0; j < UNROLL; ++j)
            zb[j] = img[ybp[j] * RD_W + xbp[j]];

        #pragma unroll
        for (int j = 0; j < UNROLL; ++j) {
            float diff = za[j] - zb[j];
            float gt   = (float)(odp[j] - 1);   // {-1, 0, 1}
            float mask = fabsf(gt);             // {0, 1}
            // stable softplus(-gt*diff) = max(x,0) + log1p(exp(-|x|))
            float x  = -gt * diff;
            float sp = fmaxf(x, 0.0f) + log1pf(__expf(-fabsf(x)));
            loss += mask * sp + (1.0f - mask) * diff * diff;
        }
    }

    // wave-64 shuffle reduction
    #pragma unroll
    for (int off = 32; off > 0; off >>= 1)
        loss += __shfl_down(loss, off, 64);

    __shared__ float wsum[BDIM / 64];
    int lane = threadIdx.x & 63;
    int wid  = threadIdx.x >> 6;
    if (lane == 0) wsum[wid] = loss;
    __syncthreads();

    if (threadIdx.x == 0) {
        float s = 0.0f;
        #pragma unroll
        for (int w = 0; w < BDIM / 64; ++w) s += wsum[w];
        atomicAdd(out, s * inv_total);   // pre-scaled partial: sum stays O(1)
    }
}

extern "C" void kernel_launch(void* const* d_in, const int* in_sizes, int n_in,
                              void* d_out, int out_size, void* d_ws, size_t ws_size,
                              hipStream_t stream) {
    const float* depth = (const float*)d_in[0];
    const int*   xA    = (const int*)d_in[1];
    const int*   yA    = (const int*)d_in[2];
    const int*   xB    = (const int*)d_in[3];
    const int*   yB    = (const int*)d_in[4];
    const int*   ord   = (const int*)d_in[5];
    float* out = (float*)d_out;

    int total = in_sizes[1];                 // B*N = 3,200,000 (divisible by 8)
    float inv_total = 1.0f / (float)total;

    // d_out is poisoned to 0xAA before every timed launch — zero it first.
    rd_zero_kernel<<<1, 1, 0, stream>>>(out);

    rd_loss_kernel<<<NXCD * KPB, BDIM, 0, stream>>>(   // 1568 blocks
        depth, xA, yA, xB, yB, ord, out, total, inv_total);
}